// Round 8
// baseline (197.243 us; speedup 1.0000x reference)
//
#include <hip/hip_runtime.h>

// GCN 2-layer forward — gather formulation, row-major bf16 gather table,
// MFMA (bf16 16x16x32) layer-1 GEMM, atomic-free parallel CSR build with
// single-pass LDS binB. Requires N <= 65536. Here N=50000, E=800000.
//
// h' = bf16( (x @ W) * dinv[row] )
// out[i] = act( dinv[i] * ( sum_{e: dst=i} h'[src_e] + h'[i] ) + b )

#define NBINS_CAP 256   // bin = dst>>8  (N <= 65536)
#define MAXBLK 512      // max binA chunks (E <= 512*2048)
#define CHUNK 2048      // edges per binA block
#define EBUF 6144       // binB LDS edge buffer (per-bin cnt ~4082 +- 4*64)
#define WT_LD 104       // Wt leading dim (bf16), 208B: 16B-aligned, bank-spread

typedef short short8 __attribute__((ext_vector_type(8)));
typedef float f32x4 __attribute__((ext_vector_type(4)));

__device__ __forceinline__ unsigned short f2bf(float f) {
    unsigned u = __float_as_uint(f);
    u = u + 0x7FFFu + ((u >> 16) & 1u);  // round-to-nearest-even
    return (unsigned short)(u >> 16);
}
__device__ __forceinline__ float bflo(unsigned w) { return __uint_as_float(w << 16); }
__device__ __forceinline__ float bfhi(unsigned w) { return __uint_as_float(w & 0xFFFF0000u); }

// ---------- binA: per-chunk LDS counting sort; coalesced slab write ----------
template <int NT>
__global__ __launch_bounds__(NT) void binA_kernel(const int* __restrict__ src,
                                                  const int* __restrict__ dst,
                                                  unsigned* __restrict__ slab,
                                                  int* __restrict__ cnt,
                                                  int* __restrict__ seg,
                                                  int nbins, int E) {
    constexpr int PT = CHUNK / NT;
    __shared__ unsigned ebuf[CHUNK];
    __shared__ int hist[NBINS_CAP];
    __shared__ int cur[NBINS_CAP];
    __shared__ int sc[NT];
    const int tid = threadIdx.x;
    const int beg = blockIdx.x * CHUNK;
    const int cntE = min(CHUNK, E - beg);
    for (int i = tid; i < nbins; i += NT) hist[i] = 0;
    __syncthreads();
    unsigned pv[PT];
    int pb[PT];
#pragma unroll
    for (int j = 0; j < PT; ++j) {
        int idx = j * NT + tid;
        if (idx < cntE) {
            int e = beg + idx;
            int s = src[e], d = dst[e];
            pb[j] = d >> 8;
            pv[j] = ((unsigned)(d & 255) << 16) | (unsigned)s;
            atomicAdd(&hist[pb[j]], 1);
        } else {
            pb[j] = -1;
        }
    }
    __syncthreads();
    int v = (tid < nbins) ? hist[tid] : 0;
    sc[tid] = v;
    __syncthreads();
    for (int off = 1; off < NT; off <<= 1) {
        int t = (tid >= off) ? sc[tid - off] : 0;
        __syncthreads();
        sc[tid] += t;
        __syncthreads();
    }
    if (tid < nbins) cur[tid] = sc[tid] - v;
    __syncthreads();
#pragma unroll
    for (int j = 0; j < PT; ++j) {
        if (pb[j] >= 0) {
            int pos = atomicAdd(&cur[pb[j]], 1);
            ebuf[pos] = pv[j];
        }
    }
    __syncthreads();
    for (int i = tid; i < cntE; i += NT) slab[beg + i] = ebuf[i];  // coalesced
    for (int i = tid; i < nbins; i += NT) {
        cnt[blockIdx.x * nbins + i] = hist[i];
        seg[blockIdx.x * nbins + i] = cur[i] - hist[i];
    }
}

// ---------- binpre: per-bin totals over chunks + exclusive scan (one block) ----------
__global__ __launch_bounds__(256) void binpre_kernel(const int* __restrict__ cnt,
                                                     int* __restrict__ binbase,
                                                     int* __restrict__ row_ptr,
                                                     int nbins, int nblk, int n, int E) {
    __shared__ int s[256];
    const int tid = threadIdx.x;
    int v = 0;
    if (tid < nbins)
        for (int b = 0; b < nblk; ++b) v += cnt[b * nbins + tid];  // coalesced across tids
    s[tid] = v;
    __syncthreads();
    for (int off = 1; off < 256; off <<= 1) {
        int t = (tid >= off) ? s[tid - off] : 0;
        __syncthreads();
        s[tid] += t;
        __syncthreads();
    }
    if (tid < nbins) binbase[tid] = s[tid] - v;
    if (tid == 0) row_ptr[n] = E;
}

// ---------- binB: per-bin merge via LDS buffer — dinv/row_ptr + contiguous esrc ----------
__global__ __launch_bounds__(256) void binB_kernel(const unsigned* __restrict__ slab,
                                                   const int* __restrict__ cnt,
                                                   const int* __restrict__ seg,
                                                   const int* __restrict__ binbase,
                                                   float* __restrict__ dinv,
                                                   int* __restrict__ row_ptr,
                                                   int* __restrict__ esrc,
                                                   int n, int nbins, int nblk) {
    constexpr int NT = 256;
    __shared__ int segc[MAXBLK], pref[MAXBLK];
    __shared__ unsigned ebuf[EBUF];
    __shared__ int sc[NT];
    __shared__ int hist[256], lbase[256], cur[256];
    const int tid = threadIdx.x;
    const int bin = blockIdx.x;
    for (int b = tid; b < MAXBLK; b += NT)
        segc[b] = (b < nblk) ? cnt[b * nbins + bin] : 0;
    __syncthreads();
    // pair-scan of segment counts -> ebuf offsets
    int ps = segc[2 * tid] + segc[2 * tid + 1];
    sc[tid] = ps;
    __syncthreads();
    for (int off = 1; off < NT; off <<= 1) {
        int t = (tid >= off) ? sc[tid - off] : 0;
        __syncthreads();
        sc[tid] += t;
        __syncthreads();
    }
    pref[2 * tid] = sc[tid] - ps;
    pref[2 * tid + 1] = sc[tid] - ps + segc[2 * tid];
    __syncthreads();
    const int total = sc[NT - 1];
    const int base = binbase[bin];
    hist[tid] = 0;
    __syncthreads();

    if (total <= EBUF) {
        // stage all of this bin's edges into LDS (single global pass)
        for (int b = tid; b < nblk; b += NT) {
            int c = segc[b];
            if (c) {
                const unsigned* p = slab + (size_t)b * CHUNK + seg[b * nbins + bin];
                int o = pref[b];
                for (int i = 0; i < c; ++i) ebuf[o + i] = p[i];
            }
        }
        __syncthreads();
        for (int i = tid; i < total; i += NT) atomicAdd(&hist[ebuf[i] >> 16], 1);
        __syncthreads();
        int v = hist[tid];
        sc[tid] = v;
        __syncthreads();
        for (int off = 1; off < NT; off <<= 1) {
            int t = (tid >= off) ? sc[tid - off] : 0;
            __syncthreads();
            sc[tid] += t;
            __syncthreads();
        }
        lbase[tid] = sc[tid] - v;
        cur[tid] = 0;
        const int node = bin * 256 + tid;
        if (node < n) {
            dinv[node] = rsqrtf((float)v + 1.0f);  // +1 = self loop
            row_ptr[node] = base + lbase[tid];
        }
        __syncthreads();
        for (int i = tid; i < total; i += NT) {
            unsigned e = ebuf[i];
            int local = e >> 16;
            int pos = base + lbase[local] + atomicAdd(&cur[local], 1);
            esrc[pos] = (int)(e & 0xFFFFu);
        }
    } else {
        // fallback: two global passes (never hit at this problem size)
        for (int b = tid; b < nblk; b += NT) {
            int c = segc[b];
            const unsigned* p = slab + (size_t)b * CHUNK + seg[b * nbins + bin];
            for (int i = 0; i < c; ++i) atomicAdd(&hist[p[i] >> 16], 1);
        }
        __syncthreads();
        int v = hist[tid];
        sc[tid] = v;
        __syncthreads();
        for (int off = 1; off < NT; off <<= 1) {
            int t = (tid >= off) ? sc[tid - off] : 0;
            __syncthreads();
            sc[tid] += t;
            __syncthreads();
        }
        lbase[tid] = sc[tid] - v;
        cur[tid] = 0;
        const int node = bin * 256 + tid;
        if (node < n) {
            dinv[node] = rsqrtf((float)v + 1.0f);
            row_ptr[node] = base + lbase[tid];
        }
        __syncthreads();
        for (int b = tid; b < nblk; b += NT) {
            int c = segc[b];
            const unsigned* p = slab + (size_t)b * CHUNK + seg[b * nbins + bin];
            for (int i = 0; i < c; ++i) {
                unsigned e = p[i];
                int local = e >> 16;
                int pos = base + lbase[local] + atomicAdd(&cur[local], 1);
                esrc[pos] = (int)(e & 0xFFFFu);
            }
        }
    }
}

// ---------- prep_w: W1 f32 [96k][96f] -> transposed bf16 Wt [96f][WT_LD k] ----------
__global__ __launch_bounds__(256) void prep_w_kernel(const float* __restrict__ W,
                                                     unsigned short* __restrict__ Wt) {
    const int tid = threadIdx.x;
    for (int i = tid; i < 96 * 96; i += 256) {
        int k = i / 96, f = i % 96;
        Wt[f * WT_LD + k] = f2bf(W[i]);
    }
}

// ---------- gemm1 via MFMA: Hb[row][96] = bf16( dinv[row] * (X @ W1) ) ----------
// Operand swap: D = Wt_frag * x_frag -> D[feature][row]; per-lane: row = lane&15,
// features (lane>>4)*4+reg (+16*tile) -> 8B packed stores. K=96 in 3 steps of 32.
__global__ __launch_bounds__(256) void gemm1_mfma(const float* __restrict__ X,
                                                  const unsigned short* __restrict__ Wtg,
                                                  const float* __restrict__ dinv,
                                                  unsigned short* __restrict__ Hb, int n) {
    __shared__ unsigned short sWt[96 * WT_LD];  // ~20KB bf16
    const int tid = threadIdx.x;
    {
        const uint4* g = (const uint4*)Wtg;
        uint4* s = (uint4*)sWt;
        for (int i = tid; i < 96 * WT_LD * 2 / 16; i += 256) s[i] = g[i];
    }
    __syncthreads();
    const int wave = tid >> 6, lane = tid & 63;
    const int rl = lane & 15, kg = lane >> 4;  // row-local, k-group
    const int row = blockIdx.x * 64 + wave * 16 + rl;
    const int rowc = min(row, n - 1);
    const float* xp = X + (size_t)rowc * 96 + kg * 8;

    f32x4 acc[6];
#pragma unroll
    for (int t = 0; t < 6; ++t) acc[t] = {0.0f, 0.0f, 0.0f, 0.0f};

#pragma unroll
    for (int ks = 0; ks < 3; ++ks) {
        float4 u0 = ((const float4*)(xp + ks * 32))[0];
        float4 u1 = ((const float4*)(xp + ks * 32))[1];
        short8 bfrag;
        bfrag[0] = (short)f2bf(u0.x); bfrag[1] = (short)f2bf(u0.y);
        bfrag[2] = (short)f2bf(u0.z); bfrag[3] = (short)f2bf(u0.w);
        bfrag[4] = (short)f2bf(u1.x); bfrag[5] = (short)f2bf(u1.y);
        bfrag[6] = (short)f2bf(u1.z); bfrag[7] = (short)f2bf(u1.w);
#pragma unroll
        for (int t = 0; t < 6; ++t) {
            short8 afrag = *(const short8*)&sWt[(t * 16 + rl) * WT_LD + ks * 32 + kg * 8];
            acc[t] = __builtin_amdgcn_mfma_f32_16x16x32_bf16(afrag, bfrag, acc[t], 0, 0, 0);
        }
    }
    if (row < n) {
        const float di = dinv[row];
        unsigned short* op = Hb + (size_t)row * 96;
#pragma unroll
        for (int t = 0; t < 6; ++t) {
            unsigned w0 = (unsigned)f2bf(acc[t][0] * di) | ((unsigned)f2bf(acc[t][1] * di) << 16);
            unsigned w1 = (unsigned)f2bf(acc[t][2] * di) | ((unsigned)f2bf(acc[t][3] * di) << 16);
            uint2 w = {w0, w1};
            *(uint2*)(op + t * 16 + kg * 4) = w;
        }
    }
}

// ---------- gemm2 (VALU f32): Hb[row][32] = bf16( dinv[row] * (X1 @ W2) ) ----------
template <int F, int ROWS, int NT>
__global__ __launch_bounds__(NT) void gemm_tile(const float* __restrict__ X,
                                                const float* __restrict__ W,
                                                const float* __restrict__ dinv,
                                                unsigned short* __restrict__ Hb, int n) {
    constexpr int K = 96;
    constexpr int CQ2 = F / 8;
    __shared__ float sX[ROWS * K];
    __shared__ float sW[K * F];
    const int tid = threadIdx.x;
    const int row0 = blockIdx.x * ROWS;
    {
        const float4* Wv = (const float4*)W;
        float4* sWv = (float4*)sW;
        for (int i = tid; i < K * F / 4; i += NT) sWv[i] = Wv[i];
    }
    if (row0 + ROWS <= n) {
        const float4* Xv = (const float4*)(X + (size_t)row0 * K);
        float4* sXv = (float4*)sX;
        for (int i = tid; i < ROWS * K / 4; i += NT) sXv[i] = Xv[i];
    } else {
        for (int i = tid; i < ROWS * K; i += NT) {
            int r = row0 + i / K;
            sX[i] = (r < n) ? X[(size_t)r * K + (i % K)] : 0.0f;
        }
    }
    __syncthreads();
    const int rp = tid / CQ2;
    const int c = tid % CQ2;
    const int r0 = rp * 2;
    float4 a00 = {0, 0, 0, 0}, a01 = {0, 0, 0, 0};
    float4 a10 = {0, 0, 0, 0}, a11 = {0, 0, 0, 0};
    const float4* sWv = (const float4*)sW;
#pragma unroll 4
    for (int k = 0; k < K; ++k) {
        float x0 = sX[r0 * K + k];
        float x1 = sX[(r0 + 1) * K + k];
        float4 w0 = sWv[k * (F / 4) + c * 2];
        float4 w1 = sWv[k * (F / 4) + c * 2 + 1];
        a00.x += x0 * w0.x; a00.y += x0 * w0.y; a00.z += x0 * w0.z; a00.w += x0 * w0.w;
        a01.x += x0 * w1.x; a01.y += x0 * w1.y; a01.z += x0 * w1.z; a01.w += x0 * w1.w;
        a10.x += x1 * w0.x; a10.y += x1 * w0.y; a10.z += x1 * w0.z; a10.w += x1 * w0.w;
        a11.x += x1 * w1.x; a11.y += x1 * w1.y; a11.z += x1 * w1.z; a11.w += x1 * w1.w;
    }
    int ra = row0 + r0, rb = ra + 1;
    if (ra < n) {
        float d0 = dinv[ra];
        uint4 w;
        w.x = (unsigned)f2bf(a00.x * d0) | ((unsigned)f2bf(a00.y * d0) << 16);
        w.y = (unsigned)f2bf(a00.z * d0) | ((unsigned)f2bf(a00.w * d0) << 16);
        w.z = (unsigned)f2bf(a01.x * d0) | ((unsigned)f2bf(a01.y * d0) << 16);
        w.w = (unsigned)f2bf(a01.z * d0) | ((unsigned)f2bf(a01.w * d0) << 16);
        ((uint4*)(Hb + (size_t)ra * F))[c] = w;
    }
    if (rb < n) {
        float d1 = dinv[rb];
        uint4 w;
        w.x = (unsigned)f2bf(a10.x * d1) | ((unsigned)f2bf(a10.y * d1) << 16);
        w.y = (unsigned)f2bf(a10.z * d1) | ((unsigned)f2bf(a10.w * d1) << 16);
        w.z = (unsigned)f2bf(a11.x * d1) | ((unsigned)f2bf(a11.y * d1) << 16);
        w.w = (unsigned)f2bf(a11.z * d1) | ((unsigned)f2bf(a11.w * d1) << 16);
        ((uint4*)(Hb + (size_t)rb * F))[c] = w;
    }
}

// ---------- gather-aggregate + epilogue (row-major bf16 table, f32 accum) ----------
#define ACC8(vv)                                                        \
    do {                                                                \
        acc0 += bflo(vv.x); acc1 += bfhi(vv.x);                         \
        acc2 += bflo(vv.y); acc3 += bfhi(vv.y);                         \
        acc4 += bflo(vv.z); acc5 += bfhi(vv.z);                         \
        acc6 += bflo(vv.w); acc7 += bfhi(vv.w);                         \
    } while (0)

template <int FC, int NPB, bool RELU, int NT>
__global__ __launch_bounds__(NT) void agg_kernel(const uint4* __restrict__ H,
                                                 const int* __restrict__ row_ptr,
                                                 const int* __restrict__ esrc,
                                                 const float* __restrict__ dinv,
                                                 const float* __restrict__ b,
                                                 float* __restrict__ out, int n) {
    constexpr int F = FC * 8;
    const int tid = threadIdx.x;
    const int node = blockIdx.x * NPB + tid / FC;
    const int q = tid % FC;
    if (node >= n) return;
    float acc0 = 0, acc1 = 0, acc2 = 0, acc3 = 0, acc4 = 0, acc5 = 0, acc6 = 0, acc7 = 0;
    {
        uint4 v = H[(size_t)node * FC + q];  // self loop
        ACC8(v);
    }
    const int beg = row_ptr[node], end = row_ptr[node + 1];
    int e = beg;
    for (; e + 4 <= end; e += 4) {
        int s0 = esrc[e + 0], s1 = esrc[e + 1], s2 = esrc[e + 2], s3 = esrc[e + 3];
        uint4 v0 = H[(size_t)s0 * FC + q];
        uint4 v1 = H[(size_t)s1 * FC + q];
        uint4 v2 = H[(size_t)s2 * FC + q];
        uint4 v3 = H[(size_t)s3 * FC + q];
        ACC8(v0); ACC8(v1); ACC8(v2); ACC8(v3);
    }
    for (; e < end; ++e) {
        uint4 v = H[(size_t)esrc[e] * FC + q];
        ACC8(v);
    }
    const float di = dinv[node];
    const int f0 = q * 8;
    float4 o0, o1;
    o0.x = acc0 * di + b[f0 + 0];
    o0.y = acc1 * di + b[f0 + 1];
    o0.z = acc2 * di + b[f0 + 2];
    o0.w = acc3 * di + b[f0 + 3];
    o1.x = acc4 * di + b[f0 + 4];
    o1.y = acc5 * di + b[f0 + 5];
    o1.z = acc6 * di + b[f0 + 6];
    o1.w = acc7 * di + b[f0 + 7];
    if (RELU) {
        o0.x = fmaxf(o0.x, 0.0f); o0.y = fmaxf(o0.y, 0.0f);
        o0.z = fmaxf(o0.z, 0.0f); o0.w = fmaxf(o0.w, 0.0f);
        o1.x = fmaxf(o1.x, 0.0f); o1.y = fmaxf(o1.y, 0.0f);
        o1.z = fmaxf(o1.z, 0.0f); o1.w = fmaxf(o1.w, 0.0f);
    }
    float4* op = (float4*)(out + (size_t)node * F);
    op[q * 2 + 0] = o0;
    op[q * 2 + 1] = o1;
}

extern "C" void kernel_launch(void* const* d_in, const int* in_sizes, int n_in,
                              void* d_out, int out_size, void* d_ws, size_t ws_size,
                              hipStream_t stream) {
    const float* x   = (const float*)d_in[0];
    const int*  eidx = (const int*)d_in[1];
    const float* W1  = (const float*)d_in[2];
    const float* b1  = (const float*)d_in[3];
    const float* W2  = (const float*)d_in[4];
    const float* b2  = (const float*)d_in[5];

    const int IN = 96, HID = 96, OUT = 32;
    const int N = in_sizes[0] / IN;   // 50000 (<= 65536 for 16-bit packing)
    const int E = in_sizes[1] / 2;    // 800000
    const int* src = eidx;
    const int* dst = eidx + E;

    float* out  = (float*)d_out;
    float* x1   = out;                       // [N, 96] f32
    float* out2 = out + (size_t)N * HID;     // [N, 32] f32

    const int nbins = (N + 255) / 256;        // 196
    const int nblk = (E + CHUNK - 1) / CHUNK; // 391 (<= MAXBLK)

    auto align512 = [](size_t v) { return ((v + 511) / 512) * 512; };
    char* ws = (char*)d_ws;
    size_t off = 0;
    float* dinv     = (float*)(ws + off); off += align512((size_t)N * 4);
    int* row_ptr    = (int*)(ws + off);   off += align512((size_t)(N + 1) * 4);
    int* esrc       = (int*)(ws + off);   off += align512((size_t)E * 4);
    unsigned* slab  = (unsigned*)(ws + off); off += align512((size_t)E * 4);
    int* cnt        = (int*)(ws + off);   off += align512((size_t)nblk * nbins * 4);
    int* seg        = (int*)(ws + off);   off += align512((size_t)nblk * nbins * 4);
    int* binbase    = (int*)(ws + off);   off += align512(NBINS_CAP * 4);
    unsigned short* wtg = (unsigned short*)(ws + off); off += align512(96 * WT_LD * 2);
    unsigned short* hb  = (unsigned short*)(ws + off); off += align512((size_t)N * 96 * 2);

    // ---- CSR build (atomic-free, fully parallel) + W1 transpose ----
    binA_kernel<256><<<nblk, 256, 0, stream>>>(src, dst, slab, cnt, seg, nbins, E);
    binpre_kernel<<<1, 256, 0, stream>>>(cnt, binbase, row_ptr, nbins, nblk, N, E);
    prep_w_kernel<<<1, 256, 0, stream>>>(W1, wtg);
    binB_kernel<<<nbins, 256, 0, stream>>>(slab, cnt, seg, binbase,
                                           dinv, row_ptr, esrc, N, nbins, nblk);

    // ---- Layer 1 (MFMA GEMM) ----
    gemm1_mfma<<<(N + 63) / 64, 256, 0, stream>>>(x, wtg, dinv, hb, N);
    agg_kernel<12, 16, true, 192><<<(N + 15) / 16, 192, 0, stream>>>(
        (const uint4*)hb, row_ptr, esrc, dinv, b1, x1, N);

    // ---- Layer 2 (f32 VALU GEMM, protects accuracy margin) ----
    gemm_tile<32, 64, 128><<<(N + 63) / 64, 128, 0, stream>>>(x1, W2, dinv, hb, N);
    agg_kernel<4, 64, false, 256><<<(N + 63) / 64, 256, 0, stream>>>(
        (const uint4*)hb, row_ptr, esrc, dinv, b2, out2, N);
}

// Round 9
// 105.171 us; speedup vs baseline: 1.8754x; 1.8754x over previous
//
#include <hip/hip_runtime.h>

// GCN 2-layer forward — gather formulation, row-major bf16 gather table,
// MFMA (bf16 16x16x32) layer-1 GEMM, atomic-free parallel CSR build with
// single-pass LDS binB. Requires N <= 65536. Here N=50000, E=800000.
//
// h' = bf16( (x @ W) * dinv[row] )
// out[i] = act( dinv[i] * ( sum_{e: dst=i} h'[src_e] + h'[i] ) + b )

#define NBINS_CAP 256   // bin = dst>>8  (N <= 65536)
#define MAXBLK 512      // max binA chunks (E <= 512*2048)
#define CHUNK 2048      // edges per binA block
#define EBUF 6144       // binB LDS edge buffer (per-bin cnt ~4082 +- 4*64)
#define WT_LD 104       // Wt leading dim (bf16), 208B: 16B-aligned, bank-spread

typedef short short8 __attribute__((ext_vector_type(8)));
typedef float f32x4 __attribute__((ext_vector_type(4)));

__device__ __forceinline__ unsigned short f2bf(float f) {
    unsigned u = __float_as_uint(f);
    u = u + 0x7FFFu + ((u >> 16) & 1u);  // round-to-nearest-even
    return (unsigned short)(u >> 16);
}
__device__ __forceinline__ float bflo(unsigned w) { return __uint_as_float(w << 16); }
__device__ __forceinline__ float bfhi(unsigned w) { return __uint_as_float(w & 0xFFFF0000u); }

// ---------- binA: per-chunk LDS counting sort; coalesced slab write ----------
template <int NT>
__global__ __launch_bounds__(NT) void binA_kernel(const int* __restrict__ src,
                                                  const int* __restrict__ dst,
                                                  unsigned* __restrict__ slab,
                                                  int* __restrict__ cnt,
                                                  int* __restrict__ seg,
                                                  int nbins, int E) {
    constexpr int PT = CHUNK / NT;
    __shared__ unsigned ebuf[CHUNK];
    __shared__ int hist[NBINS_CAP];
    __shared__ int cur[NBINS_CAP];
    __shared__ int sc[NT];
    const int tid = threadIdx.x;
    const int beg = blockIdx.x * CHUNK;
    const int cntE = min(CHUNK, E - beg);
    for (int i = tid; i < nbins; i += NT) hist[i] = 0;
    __syncthreads();
    unsigned pv[PT];
    int pb[PT];
#pragma unroll
    for (int j = 0; j < PT; ++j) {
        int idx = j * NT + tid;
        if (idx < cntE) {
            int e = beg + idx;
            int s = src[e], d = dst[e];
            pb[j] = d >> 8;
            pv[j] = ((unsigned)(d & 255) << 16) | (unsigned)s;
            atomicAdd(&hist[pb[j]], 1);
        } else {
            pb[j] = -1;
        }
    }
    __syncthreads();
    int v = (tid < nbins) ? hist[tid] : 0;
    sc[tid] = v;
    __syncthreads();
    for (int off = 1; off < NT; off <<= 1) {
        int t = (tid >= off) ? sc[tid - off] : 0;
        __syncthreads();
        sc[tid] += t;
        __syncthreads();
    }
    if (tid < nbins) cur[tid] = sc[tid] - v;
    __syncthreads();
#pragma unroll
    for (int j = 0; j < PT; ++j) {
        if (pb[j] >= 0) {
            int pos = atomicAdd(&cur[pb[j]], 1);
            ebuf[pos] = pv[j];
        }
    }
    __syncthreads();
    for (int i = tid; i < cntE; i += NT) slab[beg + i] = ebuf[i];  // coalesced
    for (int i = tid; i < nbins; i += NT) {
        cnt[blockIdx.x * nbins + i] = hist[i];
        seg[blockIdx.x * nbins + i] = cur[i] - hist[i];
    }
}

// ---------- binsum: per-bin total over chunks (one block per bin) ----------
__global__ __launch_bounds__(256) void binsum_kernel(const int* __restrict__ cnt,
                                                     int* __restrict__ btotal,
                                                     int nbins, int nblk) {
    __shared__ int r[256];
    const int bin = blockIdx.x, tid = threadIdx.x;
    int s = 0;
    for (int b = tid; b < nblk; b += 256) s += cnt[b * nbins + bin];
    r[tid] = s;
    __syncthreads();
    for (int off = 128; off; off >>= 1) {
        if (tid < off) r[tid] += r[tid + off];
        __syncthreads();
    }
    if (tid == 0) btotal[bin] = r[0];
}

// ---------- binscan: exclusive scan of bin totals (tiny) ----------
__global__ __launch_bounds__(256) void binscan_kernel(const int* __restrict__ btotal,
                                                      int* __restrict__ binbase,
                                                      int* __restrict__ row_ptr,
                                                      int nbins, int n, int E) {
    __shared__ int s[256];
    const int tid = threadIdx.x;
    int v = (tid < nbins) ? btotal[tid] : 0;
    s[tid] = v;
    __syncthreads();
    for (int off = 1; off < 256; off <<= 1) {
        int t = (tid >= off) ? s[tid - off] : 0;
        __syncthreads();
        s[tid] += t;
        __syncthreads();
    }
    if (tid < nbins) binbase[tid] = s[tid] - v;
    if (tid == 0) row_ptr[n] = E;
}

// ---------- binB: per-bin merge via LDS buffer — dinv/row_ptr + contiguous esrc ----------
__global__ __launch_bounds__(256) void binB_kernel(const unsigned* __restrict__ slab,
                                                   const int* __restrict__ cnt,
                                                   const int* __restrict__ seg,
                                                   const int* __restrict__ binbase,
                                                   float* __restrict__ dinv,
                                                   int* __restrict__ row_ptr,
                                                   int* __restrict__ esrc,
                                                   int n, int nbins, int nblk) {
    constexpr int NT = 256;
    __shared__ int segc[MAXBLK], pref[MAXBLK];
    __shared__ unsigned ebuf[EBUF];
    __shared__ int sc[NT];
    __shared__ int hist[256], lbase[256], cur[256];
    const int tid = threadIdx.x;
    const int bin = blockIdx.x;
    for (int b = tid; b < MAXBLK; b += NT)
        segc[b] = (b < nblk) ? cnt[b * nbins + bin] : 0;
    __syncthreads();
    // pair-scan of segment counts -> ebuf offsets
    int ps = segc[2 * tid] + segc[2 * tid + 1];
    sc[tid] = ps;
    __syncthreads();
    for (int off = 1; off < NT; off <<= 1) {
        int t = (tid >= off) ? sc[tid - off] : 0;
        __syncthreads();
        sc[tid] += t;
        __syncthreads();
    }
    pref[2 * tid] = sc[tid] - ps;
    pref[2 * tid + 1] = sc[tid] - ps + segc[2 * tid];
    __syncthreads();
    const int total = sc[NT - 1];
    const int base = binbase[bin];
    hist[tid] = 0;
    __syncthreads();

    if (total <= EBUF) {
        // stage all of this bin's edges into LDS (single global pass)
        for (int b = tid; b < nblk; b += NT) {
            int c = segc[b];
            if (c) {
                const unsigned* p = slab + (size_t)b * CHUNK + seg[b * nbins + bin];
                int o = pref[b];
                for (int i = 0; i < c; ++i) ebuf[o + i] = p[i];
            }
        }
        __syncthreads();
        for (int i = tid; i < total; i += NT) atomicAdd(&hist[ebuf[i] >> 16], 1);
        __syncthreads();
        int v = hist[tid];
        sc[tid] = v;
        __syncthreads();
        for (int off = 1; off < NT; off <<= 1) {
            int t = (tid >= off) ? sc[tid - off] : 0;
            __syncthreads();
            sc[tid] += t;
            __syncthreads();
        }
        lbase[tid] = sc[tid] - v;
        cur[tid] = 0;
        const int node = bin * 256 + tid;
        if (node < n) {
            dinv[node] = rsqrtf((float)v + 1.0f);  // +1 = self loop
            row_ptr[node] = base + lbase[tid];
        }
        __syncthreads();
        for (int i = tid; i < total; i += NT) {
            unsigned e = ebuf[i];
            int local = e >> 16;
            int pos = base + lbase[local] + atomicAdd(&cur[local], 1);
            esrc[pos] = (int)(e & 0xFFFFu);
        }
    } else {
        // fallback: two global passes (never hit at this problem size)
        for (int b = tid; b < nblk; b += NT) {
            int c = segc[b];
            const unsigned* p = slab + (size_t)b * CHUNK + seg[b * nbins + bin];
            for (int i = 0; i < c; ++i) atomicAdd(&hist[p[i] >> 16], 1);
        }
        __syncthreads();
        int v = hist[tid];
        sc[tid] = v;
        __syncthreads();
        for (int off = 1; off < NT; off <<= 1) {
            int t = (tid >= off) ? sc[tid - off] : 0;
            __syncthreads();
            sc[tid] += t;
            __syncthreads();
        }
        lbase[tid] = sc[tid] - v;
        cur[tid] = 0;
        const int node = bin * 256 + tid;
        if (node < n) {
            dinv[node] = rsqrtf((float)v + 1.0f);
            row_ptr[node] = base + lbase[tid];
        }
        __syncthreads();
        for (int b = tid; b < nblk; b += NT) {
            int c = segc[b];
            const unsigned* p = slab + (size_t)b * CHUNK + seg[b * nbins + bin];
            for (int i = 0; i < c; ++i) {
                unsigned e = p[i];
                int local = e >> 16;
                int pos = base + lbase[local] + atomicAdd(&cur[local], 1);
                esrc[pos] = (int)(e & 0xFFFFu);
            }
        }
    }
}

// ---------- prep_w: W1 f32 [96k][96f] -> transposed bf16 Wt [96f][WT_LD k] ----------
__global__ __launch_bounds__(256) void prep_w_kernel(const float* __restrict__ W,
                                                     unsigned short* __restrict__ Wt) {
    const int tid = threadIdx.x;
    for (int i = tid; i < 96 * 96; i += 256) {
        int k = i / 96, f = i % 96;
        Wt[f * WT_LD + k] = f2bf(W[i]);
    }
}

// ---------- gemm1 via MFMA: Hb[row][96] = bf16( dinv[row] * (X @ W1) ) ----------
// Operand swap: D = Wt_frag * x_frag -> D[feature][row]; per-lane: row = lane&15,
// features (lane>>4)*4+reg (+16*tile) -> 8B packed stores. K=96 in 3 steps of 32.
__global__ __launch_bounds__(256) void gemm1_mfma(const float* __restrict__ X,
                                                  const unsigned short* __restrict__ Wtg,
                                                  const float* __restrict__ dinv,
                                                  unsigned short* __restrict__ Hb, int n) {
    __shared__ unsigned short sWt[96 * WT_LD];  // ~20KB bf16
    const int tid = threadIdx.x;
    {
        const uint4* g = (const uint4*)Wtg;
        uint4* s = (uint4*)sWt;
        for (int i = tid; i < 96 * WT_LD * 2 / 16; i += 256) s[i] = g[i];
    }
    __syncthreads();
    const int wave = tid >> 6, lane = tid & 63;
    const int rl = lane & 15, kg = lane >> 4;  // row-local, k-group
    const int row = blockIdx.x * 64 + wave * 16 + rl;
    const int rowc = min(row, n - 1);
    const float* xp = X + (size_t)rowc * 96 + kg * 8;

    f32x4 acc[6];
#pragma unroll
    for (int t = 0; t < 6; ++t) acc[t] = {0.0f, 0.0f, 0.0f, 0.0f};

#pragma unroll
    for (int ks = 0; ks < 3; ++ks) {
        float4 u0 = ((const float4*)(xp + ks * 32))[0];
        float4 u1 = ((const float4*)(xp + ks * 32))[1];
        short8 bfrag;
        bfrag[0] = (short)f2bf(u0.x); bfrag[1] = (short)f2bf(u0.y);
        bfrag[2] = (short)f2bf(u0.z); bfrag[3] = (short)f2bf(u0.w);
        bfrag[4] = (short)f2bf(u1.x); bfrag[5] = (short)f2bf(u1.y);
        bfrag[6] = (short)f2bf(u1.z); bfrag[7] = (short)f2bf(u1.w);
#pragma unroll
        for (int t = 0; t < 6; ++t) {
            short8 afrag = *(const short8*)&sWt[(t * 16 + rl) * WT_LD + ks * 32 + kg * 8];
            acc[t] = __builtin_amdgcn_mfma_f32_16x16x32_bf16(afrag, bfrag, acc[t], 0, 0, 0);
        }
    }
    if (row < n) {
        const float di = dinv[row];
        unsigned short* op = Hb + (size_t)row * 96;
#pragma unroll
        for (int t = 0; t < 6; ++t) {
            unsigned w0 = (unsigned)f2bf(acc[t][0] * di) | ((unsigned)f2bf(acc[t][1] * di) << 16);
            unsigned w1 = (unsigned)f2bf(acc[t][2] * di) | ((unsigned)f2bf(acc[t][3] * di) << 16);
            uint2 w = {w0, w1};
            *(uint2*)(op + t * 16 + kg * 4) = w;
        }
    }
}

// ---------- gemm2 (VALU f32): Hb[row][32] = bf16( dinv[row] * (X1 @ W2) ) ----------
template <int F, int ROWS, int NT>
__global__ __launch_bounds__(NT) void gemm_tile(const float* __restrict__ X,
                                                const float* __restrict__ W,
                                                const float* __restrict__ dinv,
                                                unsigned short* __restrict__ Hb, int n) {
    constexpr int K = 96;
    constexpr int CQ2 = F / 8;
    __shared__ float sX[ROWS * K];
    __shared__ float sW[K * F];
    const int tid = threadIdx.x;
    const int row0 = blockIdx.x * ROWS;
    {
        const float4* Wv = (const float4*)W;
        float4* sWv = (float4*)sW;
        for (int i = tid; i < K * F / 4; i += NT) sWv[i] = Wv[i];
    }
    if (row0 + ROWS <= n) {
        const float4* Xv = (const float4*)(X + (size_t)row0 * K);
        float4* sXv = (float4*)sX;
        for (int i = tid; i < ROWS * K / 4; i += NT) sXv[i] = Xv[i];
    } else {
        for (int i = tid; i < ROWS * K; i += NT) {
            int r = row0 + i / K;
            sX[i] = (r < n) ? X[(size_t)r * K + (i % K)] : 0.0f;
        }
    }
    __syncthreads();
    const int rp = tid / CQ2;
    const int c = tid % CQ2;
    const int r0 = rp * 2;
    float4 a00 = {0, 0, 0, 0}, a01 = {0, 0, 0, 0};
    float4 a10 = {0, 0, 0, 0}, a11 = {0, 0, 0, 0};
    const float4* sWv = (const float4*)sW;
#pragma unroll 4
    for (int k = 0; k < K; ++k) {
        float x0 = sX[r0 * K + k];
        float x1 = sX[(r0 + 1) * K + k];
        float4 w0 = sWv[k * (F / 4) + c * 2];
        float4 w1 = sWv[k * (F / 4) + c * 2 + 1];
        a00.x += x0 * w0.x; a00.y += x0 * w0.y; a00.z += x0 * w0.z; a00.w += x0 * w0.w;
        a01.x += x0 * w1.x; a01.y += x0 * w1.y; a01.z += x0 * w1.z; a01.w += x0 * w1.w;
        a10.x += x1 * w0.x; a10.y += x1 * w0.y; a10.z += x1 * w0.z; a10.w += x1 * w0.w;
        a11.x += x1 * w1.x; a11.y += x1 * w1.y; a11.z += x1 * w1.z; a11.w += x1 * w1.w;
    }
    int ra = row0 + r0, rb = ra + 1;
    if (ra < n) {
        float d0 = dinv[ra];
        uint4 w;
        w.x = (unsigned)f2bf(a00.x * d0) | ((unsigned)f2bf(a00.y * d0) << 16);
        w.y = (unsigned)f2bf(a00.z * d0) | ((unsigned)f2bf(a00.w * d0) << 16);
        w.z = (unsigned)f2bf(a01.x * d0) | ((unsigned)f2bf(a01.y * d0) << 16);
        w.w = (unsigned)f2bf(a01.z * d0) | ((unsigned)f2bf(a01.w * d0) << 16);
        ((uint4*)(Hb + (size_t)ra * F))[c] = w;
    }
    if (rb < n) {
        float d1 = dinv[rb];
        uint4 w;
        w.x = (unsigned)f2bf(a10.x * d1) | ((unsigned)f2bf(a10.y * d1) << 16);
        w.y = (unsigned)f2bf(a10.z * d1) | ((unsigned)f2bf(a10.w * d1) << 16);
        w.z = (unsigned)f2bf(a11.x * d1) | ((unsigned)f2bf(a11.y * d1) << 16);
        w.w = (unsigned)f2bf(a11.z * d1) | ((unsigned)f2bf(a11.w * d1) << 16);
        ((uint4*)(Hb + (size_t)rb * F))[c] = w;
    }
}

// ---------- gather-aggregate + epilogue (row-major bf16 table, f32 accum) ----------
#define ACC8(vv)                                                        \
    do {                                                                \
        acc0 += bflo(vv.x); acc1 += bfhi(vv.x);                         \
        acc2 += bflo(vv.y); acc3 += bfhi(vv.y);                         \
        acc4 += bflo(vv.z); acc5 += bfhi(vv.z);                         \
        acc6 += bflo(vv.w); acc7 += bfhi(vv.w);                         \
    } while (0)

template <int FC, int NPB, bool RELU, int NT>
__global__ __launch_bounds__(NT) void agg_kernel(const uint4* __restrict__ H,
                                                 const int* __restrict__ row_ptr,
                                                 const int* __restrict__ esrc,
                                                 const float* __restrict__ dinv,
                                                 const float* __restrict__ b,
                                                 float* __restrict__ out, int n) {
    constexpr int F = FC * 8;
    const int tid = threadIdx.x;
    const int node = blockIdx.x * NPB + tid / FC;
    const int q = tid % FC;
    if (node >= n) return;
    float acc0 = 0, acc1 = 0, acc2 = 0, acc3 = 0, acc4 = 0, acc5 = 0, acc6 = 0, acc7 = 0;
    {
        uint4 v = H[(size_t)node * FC + q];  // self loop
        ACC8(v);
    }
    const int beg = row_ptr[node], end = row_ptr[node + 1];
    int e = beg;
    for (; e + 4 <= end; e += 4) {
        int s0 = esrc[e + 0], s1 = esrc[e + 1], s2 = esrc[e + 2], s3 = esrc[e + 3];
        uint4 v0 = H[(size_t)s0 * FC + q];
        uint4 v1 = H[(size_t)s1 * FC + q];
        uint4 v2 = H[(size_t)s2 * FC + q];
        uint4 v3 = H[(size_t)s3 * FC + q];
        ACC8(v0); ACC8(v1); ACC8(v2); ACC8(v3);
    }
    for (; e < end; ++e) {
        uint4 v = H[(size_t)esrc[e] * FC + q];
        ACC8(v);
    }
    const float di = dinv[node];
    const int f0 = q * 8;
    float4 o0, o1;
    o0.x = acc0 * di + b[f0 + 0];
    o0.y = acc1 * di + b[f0 + 1];
    o0.z = acc2 * di + b[f0 + 2];
    o0.w = acc3 * di + b[f0 + 3];
    o1.x = acc4 * di + b[f0 + 4];
    o1.y = acc5 * di + b[f0 + 5];
    o1.z = acc6 * di + b[f0 + 6];
    o1.w = acc7 * di + b[f0 + 7];
    if (RELU) {
        o0.x = fmaxf(o0.x, 0.0f); o0.y = fmaxf(o0.y, 0.0f);
        o0.z = fmaxf(o0.z, 0.0f); o0.w = fmaxf(o0.w, 0.0f);
        o1.x = fmaxf(o1.x, 0.0f); o1.y = fmaxf(o1.y, 0.0f);
        o1.z = fmaxf(o1.z, 0.0f); o1.w = fmaxf(o1.w, 0.0f);
    }
    float4* op = (float4*)(out + (size_t)node * F);
    op[q * 2 + 0] = o0;
    op[q * 2 + 1] = o1;
}

extern "C" void kernel_launch(void* const* d_in, const int* in_sizes, int n_in,
                              void* d_out, int out_size, void* d_ws, size_t ws_size,
                              hipStream_t stream) {
    const float* x   = (const float*)d_in[0];
    const int*  eidx = (const int*)d_in[1];
    const float* W1  = (const float*)d_in[2];
    const float* b1  = (const float*)d_in[3];
    const float* W2  = (const float*)d_in[4];
    const float* b2  = (const float*)d_in[5];

    const int IN = 96, HID = 96, OUT = 32;
    const int N = in_sizes[0] / IN;   // 50000 (<= 65536 for 16-bit packing)
    const int E = in_sizes[1] / 2;    // 800000
    const int* src = eidx;
    const int* dst = eidx + E;

    float* out  = (float*)d_out;
    float* x1   = out;                       // [N, 96] f32
    float* out2 = out + (size_t)N * HID;     // [N, 32] f32

    const int nbins = (N + 255) / 256;        // 196
    const int nblk = (E + CHUNK - 1) / CHUNK; // 391 (<= MAXBLK)

    auto align512 = [](size_t v) { return ((v + 511) / 512) * 512; };
    char* ws = (char*)d_ws;
    size_t off = 0;
    float* dinv     = (float*)(ws + off); off += align512((size_t)N * 4);
    int* row_ptr    = (int*)(ws + off);   off += align512((size_t)(N + 1) * 4);
    int* esrc       = (int*)(ws + off);   off += align512((size_t)E * 4);
    unsigned* slab  = (unsigned*)(ws + off); off += align512((size_t)E * 4);
    int* cnt        = (int*)(ws + off);   off += align512((size_t)nblk * nbins * 4);
    int* seg        = (int*)(ws + off);   off += align512((size_t)nblk * nbins * 4);
    int* btotal     = (int*)(ws + off);   off += align512(NBINS_CAP * 4);
    int* binbase    = (int*)(ws + off);   off += align512(NBINS_CAP * 4);
    unsigned short* wtg = (unsigned short*)(ws + off); off += align512(96 * WT_LD * 2);
    unsigned short* hb  = (unsigned short*)(ws + off); off += align512((size_t)N * 96 * 2);

    // ---- CSR build (atomic-free, fully parallel) + W1 transpose ----
    binA_kernel<256><<<nblk, 256, 0, stream>>>(src, dst, slab, cnt, seg, nbins, E);
    binsum_kernel<<<nbins, 256, 0, stream>>>(cnt, btotal, nbins, nblk);
    binscan_kernel<<<1, 256, 0, stream>>>(btotal, binbase, row_ptr, nbins, N, E);
    prep_w_kernel<<<1, 256, 0, stream>>>(W1, wtg);
    binB_kernel<<<nbins, 256, 0, stream>>>(slab, cnt, seg, binbase,
                                           dinv, row_ptr, esrc, N, nbins, nblk);

    // ---- Layer 1 (MFMA GEMM) ----
    gemm1_mfma<<<(N + 63) / 64, 256, 0, stream>>>(x, wtg, dinv, hb, N);
    agg_kernel<12, 16, true, 192><<<(N + 15) / 16, 192, 0, stream>>>(
        (const uint4*)hb, row_ptr, esrc, dinv, b1, x1, N);

    // ---- Layer 2 (f32 VALU GEMM, protects accuracy margin) ----
    gemm_tile<32, 64, 128><<<(N + 63) / 64, 128, 0, stream>>>(x1, W2, dinv, hb, N);
    agg_kernel<4, 64, false, 256><<<(N + 63) / 64, 256, 0, stream>>>(
        (const uint4*)hb, row_ptr, esrc, dinv, b2, out2, N);
}

// Round 10
// 83.243 us; speedup vs baseline: 2.3695x; 1.2634x over previous
//
#include <hip/hip_runtime.h>

// GCN 2-layer forward — gather formulation, row-major bf16 gather table,
// MFMA (bf16 16x16x32) for BOTH layer GEMMs, atomic-free parallel CSR build
// (transposed cnt/seg, 512-thread single-pass binB, ushort esrc).
// Requires N <= 65536 (16-bit packing). Here N=50000, E=800000.
//
// h' = bf16( (x @ W) * dinv[row] )
// out[i] = act( dinv[i] * ( sum_{e: dst=i} h'[src_e] + h'[i] ) + b )

#define NBINS_CAP 256   // bin = dst>>8  (N <= 65536)
#define MAXBLK 512      // max binA chunks (E <= 512*2048)
#define CHUNK 2048      // edges per binA block
#define EBUF 6144       // binB LDS edge buffer (per-bin cnt ~4082 +- sigma 64)
#define WT_LD 104       // Wt leading dim (bf16): 16B-aligned, bank-spread

typedef short short8 __attribute__((ext_vector_type(8)));
typedef float f32x4 __attribute__((ext_vector_type(4)));

__device__ __forceinline__ unsigned short f2bf(float f) {
    unsigned u = __float_as_uint(f);
    u = u + 0x7FFFu + ((u >> 16) & 1u);  // round-to-nearest-even
    return (unsigned short)(u >> 16);
}
__device__ __forceinline__ float bflo(unsigned w) { return __uint_as_float(w << 16); }
__device__ __forceinline__ float bfhi(unsigned w) { return __uint_as_float(w & 0xFFFF0000u); }

// ---------- binA: per-chunk LDS counting sort; coalesced slab write ----------
// cnt/seg written TRANSPOSED: [bin][chunk] so downstream reads are coalesced.
template <int NT>
__global__ __launch_bounds__(NT) void binA_kernel(const int* __restrict__ src,
                                                  const int* __restrict__ dst,
                                                  unsigned* __restrict__ slab,
                                                  int* __restrict__ cntT,
                                                  int* __restrict__ segT,
                                                  int nbins, int E) {
    constexpr int PT = CHUNK / NT;
    __shared__ unsigned ebuf[CHUNK];
    __shared__ int hist[NBINS_CAP];
    __shared__ int cur[NBINS_CAP];
    __shared__ int sc[NT];
    const int tid = threadIdx.x;
    const int beg = blockIdx.x * CHUNK;
    const int cntE = min(CHUNK, E - beg);
    for (int i = tid; i < nbins; i += NT) hist[i] = 0;
    __syncthreads();
    unsigned pv[PT];
    int pb[PT];
#pragma unroll
    for (int j = 0; j < PT; ++j) {
        int idx = j * NT + tid;
        if (idx < cntE) {
            int e = beg + idx;
            int s = src[e], d = dst[e];
            pb[j] = d >> 8;
            pv[j] = ((unsigned)(d & 255) << 16) | (unsigned)s;
            atomicAdd(&hist[pb[j]], 1);
        } else {
            pb[j] = -1;
        }
    }
    __syncthreads();
    int v = (tid < nbins) ? hist[tid] : 0;
    sc[tid] = v;
    __syncthreads();
    for (int off = 1; off < NT; off <<= 1) {
        int t = (tid >= off) ? sc[tid - off] : 0;
        __syncthreads();
        sc[tid] += t;
        __syncthreads();
    }
    if (tid < nbins) cur[tid] = sc[tid] - v;
    __syncthreads();
#pragma unroll
    for (int j = 0; j < PT; ++j) {
        if (pb[j] >= 0) {
            int pos = atomicAdd(&cur[pb[j]], 1);
            ebuf[pos] = pv[j];
        }
    }
    __syncthreads();
    for (int i = tid; i < cntE; i += NT) slab[beg + i] = ebuf[i];  // coalesced
    for (int i = tid; i < nbins; i += NT) {
        cntT[i * MAXBLK + blockIdx.x] = hist[i];           // L2 merges partial lines
        segT[i * MAXBLK + blockIdx.x] = cur[i] - hist[i];
    }
}

// ---------- binsum: per-bin totals (coalesced rows) + folded W1/W2 transpose ----------
__global__ __launch_bounds__(256) void binsum_kernel(const int* __restrict__ cntT,
                                                     int* __restrict__ btotal,
                                                     const float* __restrict__ W1,
                                                     const float* __restrict__ W2,
                                                     unsigned short* __restrict__ wtg,
                                                     unsigned short* __restrict__ wtg2,
                                                     int nbins, int nblk) {
    __shared__ int r[256];
    const int bin = blockIdx.x, tid = threadIdx.x;
    int s = 0;
    for (int b = tid; b < nblk; b += 256) s += cntT[bin * MAXBLK + b];  // coalesced
    r[tid] = s;
    __syncthreads();
    for (int off = 128; off; off >>= 1) {
        if (tid < off) r[tid] += r[tid + off];
        __syncthreads();
    }
    if (tid == 0) btotal[bin] = r[0];
    // fold: W1 (96x96) and W2 (96x32) -> transposed bf16, spread over blocks
    const int total = 96 * 96 + 96 * 32;  // 12288
    const int per = (total + nbins - 1) / nbins;
    for (int j = tid; j < per; j += 256) {
        int idx = bin * per + j;
        if (idx < 96 * 96) {
            int k = idx / 96, f = idx % 96;
            wtg[f * WT_LD + k] = f2bf(W1[idx]);
        } else if (idx < total) {
            int i2 = idx - 96 * 96;
            int k = i2 / 32, f = i2 % 32;
            wtg2[f * WT_LD + k] = f2bf(W2[i2]);
        }
    }
}

// ---------- binB: per-bin merge — self-scanned base, LDS staging, ushort esrc ----------
__global__ __launch_bounds__(512) void binB_kernel(const unsigned* __restrict__ slab,
                                                   const int* __restrict__ cntT,
                                                   const int* __restrict__ segT,
                                                   const int* __restrict__ btotal,
                                                   float* __restrict__ dinv,
                                                   int* __restrict__ row_ptr,
                                                   unsigned short* __restrict__ esrc,
                                                   int n, int nbins, int nblk, int E) {
    constexpr int NT = 512;
    __shared__ int segc[MAXBLK], pref[MAXBLK], sgs[MAXBLK];
    __shared__ unsigned ebuf[EBUF];
    __shared__ int sc[NT];
    __shared__ int bsc[256];
    __shared__ int hist[256], lbase[256], cur[256];
    const int tid = threadIdx.x;
    const int bin = blockIdx.x;

    // base = exclusive scan of btotal up to this bin (replaces binscan kernel)
    if (tid < 256) bsc[tid] = (tid < nbins) ? btotal[tid] : 0;
    __syncthreads();
    for (int off = 1; off < 256; off <<= 1) {
        int t = 0;
        if (tid < 256 && tid >= off) t = bsc[tid - off];
        __syncthreads();
        if (tid < 256) bsc[tid] += t;
        __syncthreads();
    }
    const int base = (bin > 0) ? bsc[bin - 1] : 0;
    if (bin == nbins - 1 && tid == 0) row_ptr[n] = E;
    __syncthreads();

    // coalesced loads of this bin's per-chunk counts/starts
    for (int b = tid; b < MAXBLK; b += NT) {
        segc[b] = (b < nblk) ? cntT[bin * MAXBLK + b] : 0;
        sgs[b]  = (b < nblk) ? segT[bin * MAXBLK + b] : 0;
    }
    if (tid < 256) hist[tid] = 0;
    __syncthreads();
    // 512-wide scan of segment counts -> LDS offsets
    int v = segc[tid];
    sc[tid] = v;
    __syncthreads();
    for (int off = 1; off < NT; off <<= 1) {
        int t = (tid >= off) ? sc[tid - off] : 0;
        __syncthreads();
        sc[tid] += t;
        __syncthreads();
    }
    pref[tid] = sc[tid] - v;
    __syncthreads();
    const int total = sc[NT - 1];
    const bool fits = (total <= EBUF);

    if (fits) {
        if (tid < nblk) {  // one segment per thread, single pass
            int c = segc[tid];
            const unsigned* p = slab + (size_t)tid * CHUNK + sgs[tid];
            int o = pref[tid];
            for (int i = 0; i < c; ++i) ebuf[o + i] = p[i];
        }
        __syncthreads();
        for (int i = tid; i < total; i += NT) atomicAdd(&hist[ebuf[i] >> 16], 1);
    } else {  // fallback: histogram straight from global (not hit at this size)
        for (int b = tid; b < nblk; b += NT) {
            int c = segc[b];
            const unsigned* p = slab + (size_t)b * CHUNK + sgs[b];
            for (int i = 0; i < c; ++i) atomicAdd(&hist[p[i] >> 16], 1);
        }
    }
    __syncthreads();
    // masked 256-wide scan of node histogram -> per-node bases
    int hv = 0;
    if (tid < 256) { hv = hist[tid]; bsc[tid] = hv; }
    __syncthreads();
    for (int off = 1; off < 256; off <<= 1) {
        int t = 0;
        if (tid < 256 && tid >= off) t = bsc[tid - off];
        __syncthreads();
        if (tid < 256) bsc[tid] += t;
        __syncthreads();
    }
    if (tid < 256) {
        lbase[tid] = bsc[tid] - hv;
        cur[tid] = 0;
        const int node = bin * 256 + tid;
        if (node < n) {
            dinv[node] = rsqrtf((float)hv + 1.0f);  // +1 = self loop
            row_ptr[node] = base + lbase[tid];
        }
    }
    __syncthreads();
    if (fits) {
        for (int i = tid; i < total; i += NT) {
            unsigned e = ebuf[i];
            int local = e >> 16;
            int pos = base + lbase[local] + atomicAdd(&cur[local], 1);
            esrc[pos] = (unsigned short)(e & 0xFFFFu);
        }
    } else {
        for (int b = tid; b < nblk; b += NT) {
            int c = segc[b];
            const unsigned* p = slab + (size_t)b * CHUNK + sgs[b];
            for (int i = 0; i < c; ++i) {
                unsigned e = p[i];
                int local = e >> 16;
                int pos = base + lbase[local] + atomicAdd(&cur[local], 1);
                esrc[pos] = (unsigned short)(e & 0xFFFFu);
            }
        }
    }
}

// ---------- gemm1 via MFMA: Hb[row][96] = bf16( dinv[row] * (X @ W1) ) ----------
__global__ __launch_bounds__(256) void gemm1_mfma(const float* __restrict__ X,
                                                  const unsigned short* __restrict__ Wtg,
                                                  const float* __restrict__ dinv,
                                                  unsigned short* __restrict__ Hb, int n) {
    __shared__ unsigned short sWt[96 * WT_LD];  // ~20KB bf16
    const int tid = threadIdx.x;
    {
        const uint4* g = (const uint4*)Wtg;
        uint4* s = (uint4*)sWt;
        for (int i = tid; i < 96 * WT_LD * 2 / 16; i += 256) s[i] = g[i];
    }
    __syncthreads();
    const int wave = tid >> 6, lane = tid & 63;
    const int rl = lane & 15, kg = lane >> 4;
    const int row = blockIdx.x * 64 + wave * 16 + rl;
    const int rowc = min(row, n - 1);
    const float* xp = X + (size_t)rowc * 96 + kg * 8;

    f32x4 acc[6];
#pragma unroll
    for (int t = 0; t < 6; ++t) acc[t] = {0.0f, 0.0f, 0.0f, 0.0f};

#pragma unroll
    for (int ks = 0; ks < 3; ++ks) {
        float4 u0 = ((const float4*)(xp + ks * 32))[0];
        float4 u1 = ((const float4*)(xp + ks * 32))[1];
        short8 bfrag;
        bfrag[0] = (short)f2bf(u0.x); bfrag[1] = (short)f2bf(u0.y);
        bfrag[2] = (short)f2bf(u0.z); bfrag[3] = (short)f2bf(u0.w);
        bfrag[4] = (short)f2bf(u1.x); bfrag[5] = (short)f2bf(u1.y);
        bfrag[6] = (short)f2bf(u1.z); bfrag[7] = (short)f2bf(u1.w);
#pragma unroll
        for (int t = 0; t < 6; ++t) {
            short8 afrag = *(const short8*)&sWt[(t * 16 + rl) * WT_LD + ks * 32 + kg * 8];
            acc[t] = __builtin_amdgcn_mfma_f32_16x16x32_bf16(afrag, bfrag, acc[t], 0, 0, 0);
        }
    }
    if (row < n) {
        const float di = dinv[row];
        unsigned short* op = Hb + (size_t)row * 96;
#pragma unroll
        for (int t = 0; t < 6; ++t) {
            unsigned w0 = (unsigned)f2bf(acc[t][0] * di) | ((unsigned)f2bf(acc[t][1] * di) << 16);
            unsigned w1 = (unsigned)f2bf(acc[t][2] * di) | ((unsigned)f2bf(acc[t][3] * di) << 16);
            uint2 w = {w0, w1};
            *(uint2*)(op + t * 16 + kg * 4) = w;
        }
    }
}

// ---------- gemm2 via MFMA: Hb[row][32] = bf16( dinv[row] * (X1 @ W2) ) ----------
__global__ __launch_bounds__(256) void gemm2_mfma(const float* __restrict__ X,
                                                  const unsigned short* __restrict__ Wtg2,
                                                  const float* __restrict__ dinv,
                                                  unsigned short* __restrict__ Hb, int n) {
    __shared__ unsigned short sWt[32 * WT_LD];  // ~6.7KB
    const int tid = threadIdx.x;
    {
        const uint4* g = (const uint4*)Wtg2;
        uint4* s = (uint4*)sWt;
        for (int i = tid; i < 32 * WT_LD * 2 / 16; i += 256) s[i] = g[i];
    }
    __syncthreads();
    const int wave = tid >> 6, lane = tid & 63;
    const int rl = lane & 15, kg = lane >> 4;
    const int row = blockIdx.x * 64 + wave * 16 + rl;
    const int rowc = min(row, n - 1);
    const float* xp = X + (size_t)rowc * 96 + kg * 8;

    f32x4 acc[2];
#pragma unroll
    for (int t = 0; t < 2; ++t) acc[t] = {0.0f, 0.0f, 0.0f, 0.0f};

#pragma unroll
    for (int ks = 0; ks < 3; ++ks) {
        float4 u0 = ((const float4*)(xp + ks * 32))[0];
        float4 u1 = ((const float4*)(xp + ks * 32))[1];
        short8 bfrag;
        bfrag[0] = (short)f2bf(u0.x); bfrag[1] = (short)f2bf(u0.y);
        bfrag[2] = (short)f2bf(u0.z); bfrag[3] = (short)f2bf(u0.w);
        bfrag[4] = (short)f2bf(u1.x); bfrag[5] = (short)f2bf(u1.y);
        bfrag[6] = (short)f2bf(u1.z); bfrag[7] = (short)f2bf(u1.w);
#pragma unroll
        for (int t = 0; t < 2; ++t) {
            short8 afrag = *(const short8*)&sWt[(t * 16 + rl) * WT_LD + ks * 32 + kg * 8];
            acc[t] = __builtin_amdgcn_mfma_f32_16x16x32_bf16(afrag, bfrag, acc[t], 0, 0, 0);
        }
    }
    if (row < n) {
        const float di = dinv[row];
        unsigned short* op = Hb + (size_t)row * 32;
#pragma unroll
        for (int t = 0; t < 2; ++t) {
            unsigned w0 = (unsigned)f2bf(acc[t][0] * di) | ((unsigned)f2bf(acc[t][1] * di) << 16);
            unsigned w1 = (unsigned)f2bf(acc[t][2] * di) | ((unsigned)f2bf(acc[t][3] * di) << 16);
            uint2 w = {w0, w1};
            *(uint2*)(op + t * 16 + kg * 4) = w;
        }
    }
}

// ---------- gather-aggregate + epilogue (bf16 table, f32 accum, unroll 8) ----------
#define ACC8(vv)                                                        \
    do {                                                                \
        acc0 += bflo(vv.x); acc1 += bfhi(vv.x);                         \
        acc2 += bflo(vv.y); acc3 += bfhi(vv.y);                         \
        acc4 += bflo(vv.z); acc5 += bfhi(vv.z);                         \
        acc6 += bflo(vv.w); acc7 += bfhi(vv.w);                         \
    } while (0)

template <int FC, int NPB, bool RELU, int NT>
__global__ __launch_bounds__(NT) void agg_kernel(const uint4* __restrict__ H,
                                                 const int* __restrict__ row_ptr,
                                                 const unsigned short* __restrict__ esrc,
                                                 const float* __restrict__ dinv,
                                                 const float* __restrict__ b,
                                                 float* __restrict__ out, int n) {
    constexpr int F = FC * 8;
    const int tid = threadIdx.x;
    const int node = blockIdx.x * NPB + tid / FC;
    const int q = tid % FC;
    if (node >= n) return;
    float acc0 = 0, acc1 = 0, acc2 = 0, acc3 = 0, acc4 = 0, acc5 = 0, acc6 = 0, acc7 = 0;
    {
        uint4 v = H[(size_t)node * FC + q];  // self loop
        ACC8(v);
    }
    const int beg = row_ptr[node], end = row_ptr[node + 1];
    int e = beg;
    for (; e + 8 <= end; e += 8) {
        int s0 = esrc[e + 0], s1 = esrc[e + 1], s2 = esrc[e + 2], s3 = esrc[e + 3];
        int s4 = esrc[e + 4], s5 = esrc[e + 5], s6 = esrc[e + 6], s7 = esrc[e + 7];
        uint4 v0 = H[(size_t)s0 * FC + q];
        uint4 v1 = H[(size_t)s1 * FC + q];
        uint4 v2 = H[(size_t)s2 * FC + q];
        uint4 v3 = H[(size_t)s3 * FC + q];
        uint4 v4 = H[(size_t)s4 * FC + q];
        uint4 v5 = H[(size_t)s5 * FC + q];
        uint4 v6 = H[(size_t)s6 * FC + q];
        uint4 v7 = H[(size_t)s7 * FC + q];
        ACC8(v0); ACC8(v1); ACC8(v2); ACC8(v3);
        ACC8(v4); ACC8(v5); ACC8(v6); ACC8(v7);
    }
    for (; e + 4 <= end; e += 4) {
        int s0 = esrc[e + 0], s1 = esrc[e + 1], s2 = esrc[e + 2], s3 = esrc[e + 3];
        uint4 v0 = H[(size_t)s0 * FC + q];
        uint4 v1 = H[(size_t)s1 * FC + q];
        uint4 v2 = H[(size_t)s2 * FC + q];
        uint4 v3 = H[(size_t)s3 * FC + q];
        ACC8(v0); ACC8(v1); ACC8(v2); ACC8(v3);
    }
    for (; e < end; ++e) {
        uint4 v = H[(size_t)esrc[e] * FC + q];
        ACC8(v);
    }
    const float di = dinv[node];
    const int f0 = q * 8;
    float4 o0, o1;
    o0.x = acc0 * di + b[f0 + 0];
    o0.y = acc1 * di + b[f0 + 1];
    o0.z = acc2 * di + b[f0 + 2];
    o0.w = acc3 * di + b[f0 + 3];
    o1.x = acc4 * di + b[f0 + 4];
    o1.y = acc5 * di + b[f0 + 5];
    o1.z = acc6 * di + b[f0 + 6];
    o1.w = acc7 * di + b[f0 + 7];
    if (RELU) {
        o0.x = fmaxf(o0.x, 0.0f); o0.y = fmaxf(o0.y, 0.0f);
        o0.z = fmaxf(o0.z, 0.0f); o0.w = fmaxf(o0.w, 0.0f);
        o1.x = fmaxf(o1.x, 0.0f); o1.y = fmaxf(o1.y, 0.0f);
        o1.z = fmaxf(o1.z, 0.0f); o1.w = fmaxf(o1.w, 0.0f);
    }
    float4* op = (float4*)(out + (size_t)node * F);
    op[q * 2 + 0] = o0;
    op[q * 2 + 1] = o1;
}

extern "C" void kernel_launch(void* const* d_in, const int* in_sizes, int n_in,
                              void* d_out, int out_size, void* d_ws, size_t ws_size,
                              hipStream_t stream) {
    const float* x   = (const float*)d_in[0];
    const int*  eidx = (const int*)d_in[1];
    const float* W1  = (const float*)d_in[2];
    const float* b1  = (const float*)d_in[3];
    const float* W2  = (const float*)d_in[4];
    const float* b2  = (const float*)d_in[5];

    const int IN = 96, HID = 96, OUT = 32;
    const int N = in_sizes[0] / IN;   // 50000 (<= 65536 for 16-bit packing)
    const int E = in_sizes[1] / 2;    // 800000
    const int* src = eidx;
    const int* dst = eidx + E;

    float* out  = (float*)d_out;
    float* x1   = out;                       // [N, 96] f32
    float* out2 = out + (size_t)N * HID;     // [N, 32] f32

    const int nbins = (N + 255) / 256;        // 196
    const int nblk = (E + CHUNK - 1) / CHUNK; // 391 (<= MAXBLK)

    auto align512 = [](size_t v) { return ((v + 511) / 512) * 512; };
    char* ws = (char*)d_ws;
    size_t off = 0;
    float* dinv     = (float*)(ws + off); off += align512((size_t)N * 4);
    int* row_ptr    = (int*)(ws + off);   off += align512((size_t)(N + 1) * 4);
    unsigned short* esrc = (unsigned short*)(ws + off); off += align512((size_t)E * 2);
    unsigned* slab  = (unsigned*)(ws + off); off += align512((size_t)E * 4);
    int* cntT       = (int*)(ws + off);   off += align512((size_t)NBINS_CAP * MAXBLK * 4);
    int* segT       = (int*)(ws + off);   off += align512((size_t)NBINS_CAP * MAXBLK * 4);
    int* btotal     = (int*)(ws + off);   off += align512(NBINS_CAP * 4);
    unsigned short* wtg  = (unsigned short*)(ws + off); off += align512(96 * WT_LD * 2);
    unsigned short* wtg2 = (unsigned short*)(ws + off); off += align512(32 * WT_LD * 2);
    unsigned short* hb   = (unsigned short*)(ws + off); off += align512((size_t)N * 96 * 2);

    // ---- CSR build (atomic-free) + fused W transposes ----
    binA_kernel<256><<<nblk, 256, 0, stream>>>(src, dst, slab, cntT, segT, nbins, E);
    binsum_kernel<<<nbins, 256, 0, stream>>>(cntT, btotal, W1, W2, wtg, wtg2, nbins, nblk);
    binB_kernel<<<nbins, 512, 0, stream>>>(slab, cntT, segT, btotal,
                                           dinv, row_ptr, esrc, N, nbins, nblk, E);

    // ---- Layer 1 (MFMA) ----
    gemm1_mfma<<<(N + 63) / 64, 256, 0, stream>>>(x, wtg, dinv, hb, N);
    agg_kernel<12, 16, true, 192><<<(N + 15) / 16, 192, 0, stream>>>(
        (const uint4*)hb, row_ptr, esrc, dinv, b1, x1, N);

    // ---- Layer 2 (MFMA) ----
    gemm2_mfma<<<(N + 63) / 64, 256, 0, stream>>>(x1, wtg2, dinv, hb, N);
    agg_kernel<4, 64, false, 256><<<(N + 63) / 64, 256, 0, stream>>>(
        (const uint4*)hb, row_ptr, esrc, dinv, b2, out2, N);
}

// Round 11
// 82.408 us; speedup vs baseline: 2.3935x; 1.0101x over previous
//
#include <hip/hip_runtime.h>

// GCN 2-layer forward — gather formulation, row-major bf16 gather table,
// MFMA (bf16 16x16x32) for BOTH layer GEMMs, atomic-free parallel CSR build
// (transposed cnt/seg, 512-thread single-pass binB, ushort esrc).
// Requires N <= 65536 (16-bit packing). Here N=50000, E=800000.
//
// h' = bf16( (x @ W) * dinv[row] )
// out[i] = act( dinv[i] * ( sum_{e: dst=i} h'[src_e] + h'[i] ) + b )

#define NBINS_CAP 256   // bin = dst>>8  (N <= 65536)
#define MAXBLK 512      // max binA chunks (E <= 512*2048)
#define CHUNK 2048      // edges per binA block
#define EBUF 6144       // binB LDS edge buffer (per-bin cnt ~4082 +- sigma 64)
#define WT_LD 104       // Wt leading dim (bf16): 16B-aligned, bank-spread

typedef short short8 __attribute__((ext_vector_type(8)));
typedef float f32x4 __attribute__((ext_vector_type(4)));

__device__ __forceinline__ unsigned short f2bf(float f) {
    unsigned u = __float_as_uint(f);
    u = u + 0x7FFFu + ((u >> 16) & 1u);  // round-to-nearest-even
    return (unsigned short)(u >> 16);
}
__device__ __forceinline__ float bflo(unsigned w) { return __uint_as_float(w << 16); }
__device__ __forceinline__ float bfhi(unsigned w) { return __uint_as_float(w & 0xFFFF0000u); }

// ---------- binA: per-chunk LDS counting sort; coalesced slab write ----------
// cnt/seg written TRANSPOSED: [bin][chunk] so downstream reads are coalesced.
template <int NT>
__global__ __launch_bounds__(NT) void binA_kernel(const int* __restrict__ src,
                                                  const int* __restrict__ dst,
                                                  unsigned* __restrict__ slab,
                                                  int* __restrict__ cntT,
                                                  int* __restrict__ segT,
                                                  int nbins, int E) {
    constexpr int PT = CHUNK / NT;
    __shared__ unsigned ebuf[CHUNK];
    __shared__ int hist[NBINS_CAP];
    __shared__ int cur[NBINS_CAP];
    __shared__ int sc[NT];
    const int tid = threadIdx.x;
    const int beg = blockIdx.x * CHUNK;
    const int cntE = min(CHUNK, E - beg);
    for (int i = tid; i < nbins; i += NT) hist[i] = 0;
    __syncthreads();
    unsigned pv[PT];
    int pb[PT];
#pragma unroll
    for (int j = 0; j < PT; ++j) {
        int idx = j * NT + tid;
        if (idx < cntE) {
            int e = beg + idx;
            int s = src[e], d = dst[e];
            pb[j] = d >> 8;
            pv[j] = ((unsigned)(d & 255) << 16) | (unsigned)s;
            atomicAdd(&hist[pb[j]], 1);
        } else {
            pb[j] = -1;
        }
    }
    __syncthreads();
    int v = (tid < nbins) ? hist[tid] : 0;
    sc[tid] = v;
    __syncthreads();
    for (int off = 1; off < NT; off <<= 1) {
        int t = (tid >= off) ? sc[tid - off] : 0;
        __syncthreads();
        sc[tid] += t;
        __syncthreads();
    }
    if (tid < nbins) cur[tid] = sc[tid] - v;
    __syncthreads();
#pragma unroll
    for (int j = 0; j < PT; ++j) {
        if (pb[j] >= 0) {
            int pos = atomicAdd(&cur[pb[j]], 1);
            ebuf[pos] = pv[j];
        }
    }
    __syncthreads();
    for (int i = tid; i < cntE; i += NT) slab[beg + i] = ebuf[i];  // coalesced
    for (int i = tid; i < nbins; i += NT) {
        cntT[i * MAXBLK + blockIdx.x] = hist[i];           // L2 merges partial lines
        segT[i * MAXBLK + blockIdx.x] = cur[i] - hist[i];
    }
}

// ---------- binsum: per-bin totals (coalesced rows) + folded W1/W2 transpose ----------
__global__ __launch_bounds__(256) void binsum_kernel(const int* __restrict__ cntT,
                                                     int* __restrict__ btotal,
                                                     const float* __restrict__ W1,
                                                     const float* __restrict__ W2,
                                                     unsigned short* __restrict__ wtg,
                                                     unsigned short* __restrict__ wtg2,
                                                     int nbins, int nblk) {
    __shared__ int r[256];
    const int bin = blockIdx.x, tid = threadIdx.x;
    int s = 0;
    for (int b = tid; b < nblk; b += 256) s += cntT[bin * MAXBLK + b];  // coalesced
    r[tid] = s;
    __syncthreads();
    for (int off = 128; off; off >>= 1) {
        if (tid < off) r[tid] += r[tid + off];
        __syncthreads();
    }
    if (tid == 0) btotal[bin] = r[0];
    // fold: W1 (96x96) and W2 (96x32) -> transposed bf16, spread over blocks
    const int total = 96 * 96 + 96 * 32;  // 12288
    const int per = (total + nbins - 1) / nbins;
    for (int j = tid; j < per; j += 256) {
        int idx = bin * per + j;
        if (idx < 96 * 96) {
            int k = idx / 96, f = idx % 96;
            wtg[f * WT_LD + k] = f2bf(W1[idx]);
        } else if (idx < total) {
            int i2 = idx - 96 * 96;
            int k = i2 / 32, f = i2 % 32;
            wtg2[f * WT_LD + k] = f2bf(W2[i2]);
        }
    }
}

// ---------- binB: per-bin merge — self-scanned base, LDS staging, ushort esrc ----------
__global__ __launch_bounds__(512) void binB_kernel(const unsigned* __restrict__ slab,
                                                   const int* __restrict__ cntT,
                                                   const int* __restrict__ segT,
                                                   const int* __restrict__ btotal,
                                                   float* __restrict__ dinv,
                                                   int* __restrict__ row_ptr,
                                                   unsigned short* __restrict__ esrc,
                                                   int n, int nbins, int nblk, int E) {
    constexpr int NT = 512;
    __shared__ int segc[MAXBLK], pref[MAXBLK], sgs[MAXBLK];
    __shared__ unsigned ebuf[EBUF];
    __shared__ int sc[NT];
    __shared__ int bsc[256];
    __shared__ int hist[256], lbase[256], cur[256];
    const int tid = threadIdx.x;
    const int bin = blockIdx.x;

    // base = exclusive scan of btotal up to this bin (replaces binscan kernel)
    if (tid < 256) bsc[tid] = (tid < nbins) ? btotal[tid] : 0;
    __syncthreads();
    for (int off = 1; off < 256; off <<= 1) {
        int t = 0;
        if (tid < 256 && tid >= off) t = bsc[tid - off];
        __syncthreads();
        if (tid < 256) bsc[tid] += t;
        __syncthreads();
    }
    const int base = (bin > 0) ? bsc[bin - 1] : 0;
    if (bin == nbins - 1 && tid == 0) row_ptr[n] = E;
    __syncthreads();

    // coalesced loads of this bin's per-chunk counts/starts
    for (int b = tid; b < MAXBLK; b += NT) {
        segc[b] = (b < nblk) ? cntT[bin * MAXBLK + b] : 0;
        sgs[b]  = (b < nblk) ? segT[bin * MAXBLK + b] : 0;
    }
    if (tid < 256) hist[tid] = 0;
    __syncthreads();
    // 512-wide scan of segment counts -> LDS offsets
    int v = segc[tid];
    sc[tid] = v;
    __syncthreads();
    for (int off = 1; off < NT; off <<= 1) {
        int t = (tid >= off) ? sc[tid - off] : 0;
        __syncthreads();
        sc[tid] += t;
        __syncthreads();
    }
    pref[tid] = sc[tid] - v;
    __syncthreads();
    const int total = sc[NT - 1];
    const bool fits = (total <= EBUF);

    if (fits) {
        if (tid < nblk) {  // one segment per thread, single pass
            int c = segc[tid];
            const unsigned* p = slab + (size_t)tid * CHUNK + sgs[tid];
            int o = pref[tid];
            for (int i = 0; i < c; ++i) ebuf[o + i] = p[i];
        }
        __syncthreads();
        for (int i = tid; i < total; i += NT) atomicAdd(&hist[ebuf[i] >> 16], 1);
    } else {  // fallback: histogram straight from global (not hit at this size)
        for (int b = tid; b < nblk; b += NT) {
            int c = segc[b];
            const unsigned* p = slab + (size_t)b * CHUNK + sgs[b];
            for (int i = 0; i < c; ++i) atomicAdd(&hist[p[i] >> 16], 1);
        }
    }
    __syncthreads();
    // masked 256-wide scan of node histogram -> per-node bases
    int hv = 0;
    if (tid < 256) { hv = hist[tid]; bsc[tid] = hv; }
    __syncthreads();
    for (int off = 1; off < 256; off <<= 1) {
        int t = 0;
        if (tid < 256 && tid >= off) t = bsc[tid - off];
        __syncthreads();
        if (tid < 256) bsc[tid] += t;
        __syncthreads();
    }
    if (tid < 256) {
        lbase[tid] = bsc[tid] - hv;
        cur[tid] = 0;
        const int node = bin * 256 + tid;
        if (node < n) {
            dinv[node] = rsqrtf((float)hv + 1.0f);  // +1 = self loop
            row_ptr[node] = base + lbase[tid];
        }
    }
    __syncthreads();
    if (fits) {
        for (int i = tid; i < total; i += NT) {
            unsigned e = ebuf[i];
            int local = e >> 16;
            int pos = base + lbase[local] + atomicAdd(&cur[local], 1);
            esrc[pos] = (unsigned short)(e & 0xFFFFu);
        }
    } else {
        for (int b = tid; b < nblk; b += NT) {
            int c = segc[b];
            const unsigned* p = slab + (size_t)b * CHUNK + sgs[b];
            for (int i = 0; i < c; ++i) {
                unsigned e = p[i];
                int local = e >> 16;
                int pos = base + lbase[local] + atomicAdd(&cur[local], 1);
                esrc[pos] = (unsigned short)(e & 0xFFFFu);
            }
        }
    }
}

// ---------- gemm1 via MFMA: Hb[row][96] = bf16( dinv[row] * (X @ W1) ) ----------
__global__ __launch_bounds__(256) void gemm1_mfma(const float* __restrict__ X,
                                                  const unsigned short* __restrict__ Wtg,
                                                  const float* __restrict__ dinv,
                                                  unsigned short* __restrict__ Hb, int n) {
    __shared__ unsigned short sWt[96 * WT_LD];  // ~20KB bf16
    const int tid = threadIdx.x;
    {
        const uint4* g = (const uint4*)Wtg;
        uint4* s = (uint4*)sWt;
        for (int i = tid; i < 96 * WT_LD * 2 / 16; i += 256) s[i] = g[i];
    }
    __syncthreads();
    const int wave = tid >> 6, lane = tid & 63;
    const int rl = lane & 15, kg = lane >> 4;
    const int row = blockIdx.x * 64 + wave * 16 + rl;
    const int rowc = min(row, n - 1);
    const float* xp = X + (size_t)rowc * 96 + kg * 8;

    f32x4 acc[6];
#pragma unroll
    for (int t = 0; t < 6; ++t) acc[t] = {0.0f, 0.0f, 0.0f, 0.0f};

#pragma unroll
    for (int ks = 0; ks < 3; ++ks) {
        float4 u0 = ((const float4*)(xp + ks * 32))[0];
        float4 u1 = ((const float4*)(xp + ks * 32))[1];
        short8 bfrag;
        bfrag[0] = (short)f2bf(u0.x); bfrag[1] = (short)f2bf(u0.y);
        bfrag[2] = (short)f2bf(u0.z); bfrag[3] = (short)f2bf(u0.w);
        bfrag[4] = (short)f2bf(u1.x); bfrag[5] = (short)f2bf(u1.y);
        bfrag[6] = (short)f2bf(u1.z); bfrag[7] = (short)f2bf(u1.w);
#pragma unroll
        for (int t = 0; t < 6; ++t) {
            short8 afrag = *(const short8*)&sWt[(t * 16 + rl) * WT_LD + ks * 32 + kg * 8];
            acc[t] = __builtin_amdgcn_mfma_f32_16x16x32_bf16(afrag, bfrag, acc[t], 0, 0, 0);
        }
    }
    if (row < n) {
        const float di = dinv[row];
        unsigned short* op = Hb + (size_t)row * 96;
#pragma unroll
        for (int t = 0; t < 6; ++t) {
            unsigned w0 = (unsigned)f2bf(acc[t][0] * di) | ((unsigned)f2bf(acc[t][1] * di) << 16);
            unsigned w1 = (unsigned)f2bf(acc[t][2] * di) | ((unsigned)f2bf(acc[t][3] * di) << 16);
            uint2 w = {w0, w1};
            *(uint2*)(op + t * 16 + kg * 4) = w;
        }
    }
}

// ---------- gemm2 via MFMA: Hb[row][32] = bf16( dinv[row] * (X1 @ W2) ) ----------
__global__ __launch_bounds__(256) void gemm2_mfma(const float* __restrict__ X,
                                                  const unsigned short* __restrict__ Wtg2,
                                                  const float* __restrict__ dinv,
                                                  unsigned short* __restrict__ Hb, int n) {
    __shared__ unsigned short sWt[32 * WT_LD];  // ~6.7KB
    const int tid = threadIdx.x;
    {
        const uint4* g = (const uint4*)Wtg2;
        uint4* s = (uint4*)sWt;
        for (int i = tid; i < 32 * WT_LD * 2 / 16; i += 256) s[i] = g[i];
    }
    __syncthreads();
    const int wave = tid >> 6, lane = tid & 63;
    const int rl = lane & 15, kg = lane >> 4;
    const int row = blockIdx.x * 64 + wave * 16 + rl;
    const int rowc = min(row, n - 1);
    const float* xp = X + (size_t)rowc * 96 + kg * 8;

    f32x4 acc[2];
#pragma unroll
    for (int t = 0; t < 2; ++t) acc[t] = {0.0f, 0.0f, 0.0f, 0.0f};

#pragma unroll
    for (int ks = 0; ks < 3; ++ks) {
        float4 u0 = ((const float4*)(xp + ks * 32))[0];
        float4 u1 = ((const float4*)(xp + ks * 32))[1];
        short8 bfrag;
        bfrag[0] = (short)f2bf(u0.x); bfrag[1] = (short)f2bf(u0.y);
        bfrag[2] = (short)f2bf(u0.z); bfrag[3] = (short)f2bf(u0.w);
        bfrag[4] = (short)f2bf(u1.x); bfrag[5] = (short)f2bf(u1.y);
        bfrag[6] = (short)f2bf(u1.z); bfrag[7] = (short)f2bf(u1.w);
#pragma unroll
        for (int t = 0; t < 2; ++t) {
            short8 afrag = *(const short8*)&sWt[(t * 16 + rl) * WT_LD + ks * 32 + kg * 8];
            acc[t] = __builtin_amdgcn_mfma_f32_16x16x32_bf16(afrag, bfrag, acc[t], 0, 0, 0);
        }
    }
    if (row < n) {
        const float di = dinv[row];
        unsigned short* op = Hb + (size_t)row * 32;
#pragma unroll
        for (int t = 0; t < 2; ++t) {
            unsigned w0 = (unsigned)f2bf(acc[t][0] * di) | ((unsigned)f2bf(acc[t][1] * di) << 16);
            unsigned w1 = (unsigned)f2bf(acc[t][2] * di) | ((unsigned)f2bf(acc[t][3] * di) << 16);
            uint2 w = {w0, w1};
            *(uint2*)(op + t * 16 + kg * 4) = w;
        }
    }
}

// ---------- gather-aggregate + epilogue (bf16 table, f32 accum, unroll 8) ----------
#define ACC8(vv)                                                        \
    do {                                                                \
        acc0 += bflo(vv.x); acc1 += bfhi(vv.x);                         \
        acc2 += bflo(vv.y); acc3 += bfhi(vv.y);                         \
        acc4 += bflo(vv.z); acc5 += bfhi(vv.z);                         \
        acc6 += bflo(vv.w); acc7 += bfhi(vv.w);                         \
    } while (0)

template <int FC, int NPB, bool RELU, int NT>
__global__ __launch_bounds__(NT) void agg_kernel(const uint4* __restrict__ H,
                                                 const int* __restrict__ row_ptr,
                                                 const unsigned short* __restrict__ esrc,
                                                 const float* __restrict__ dinv,
                                                 const float* __restrict__ b,
                                                 float* __restrict__ out, int n) {
    constexpr int F = FC * 8;
    const int tid = threadIdx.x;
    const int node = blockIdx.x * NPB + tid / FC;
    const int q = tid % FC;
    if (node >= n) return;
    float acc0 = 0, acc1 = 0, acc2 = 0, acc3 = 0, acc4 = 0, acc5 = 0, acc6 = 0, acc7 = 0;
    {
        uint4 v = H[(size_t)node * FC + q];  // self loop
        ACC8(v);
    }
    const int beg = row_ptr[node], end = row_ptr[node + 1];
    int e = beg;
    for (; e + 8 <= end; e += 8) {
        int s0 = esrc[e + 0], s1 = esrc[e + 1], s2 = esrc[e + 2], s3 = esrc[e + 3];
        int s4 = esrc[e + 4], s5 = esrc[e + 5], s6 = esrc[e + 6], s7 = esrc[e + 7];
        uint4 v0 = H[(size_t)s0 * FC + q];
        uint4 v1 = H[(size_t)s1 * FC + q];
        uint4 v2 = H[(size_t)s2 * FC + q];
        uint4 v3 = H[(size_t)s3 * FC + q];
        uint4 v4 = H[(size_t)s4 * FC + q];
        uint4 v5 = H[(size_t)s5 * FC + q];
        uint4 v6 = H[(size_t)s6 * FC + q];
        uint4 v7 = H[(size_t)s7 * FC + q];
        ACC8(v0); ACC8(v1); ACC8(v2); ACC8(v3);
        ACC8(v4); ACC8(v5); ACC8(v6); ACC8(v7);
    }
    for (; e + 4 <= end; e += 4) {
        int s0 = esrc[e + 0], s1 = esrc[e + 1], s2 = esrc[e + 2], s3 = esrc[e + 3];
        uint4 v0 = H[(size_t)s0 * FC + q];
        uint4 v1 = H[(size_t)s1 * FC + q];
        uint4 v2 = H[(size_t)s2 * FC + q];
        uint4 v3 = H[(size_t)s3 * FC + q];
        ACC8(v0); ACC8(v1); ACC8(v2); ACC8(v3);
    }
    for (; e < end; ++e) {
        uint4 v = H[(size_t)esrc[e] * FC + q];
        ACC8(v);
    }
    const float di = dinv[node];
    const int f0 = q * 8;
    float4 o0, o1;
    o0.x = acc0 * di + b[f0 + 0];
    o0.y = acc1 * di + b[f0 + 1];
    o0.z = acc2 * di + b[f0 + 2];
    o0.w = acc3 * di + b[f0 + 3];
    o1.x = acc4 * di + b[f0 + 4];
    o1.y = acc5 * di + b[f0 + 5];
    o1.z = acc6 * di + b[f0 + 6];
    o1.w = acc7 * di + b[f0 + 7];
    if (RELU) {
        o0.x = fmaxf(o0.x, 0.0f); o0.y = fmaxf(o0.y, 0.0f);
        o0.z = fmaxf(o0.z, 0.0f); o0.w = fmaxf(o0.w, 0.0f);
        o1.x = fmaxf(o1.x, 0.0f); o1.y = fmaxf(o1.y, 0.0f);
        o1.z = fmaxf(o1.z, 0.0f); o1.w = fmaxf(o1.w, 0.0f);
    }
    float4* op = (float4*)(out + (size_t)node * F);
    op[q * 2 + 0] = o0;
    op[q * 2 + 1] = o1;
}

extern "C" void kernel_launch(void* const* d_in, const int* in_sizes, int n_in,
                              void* d_out, int out_size, void* d_ws, size_t ws_size,
                              hipStream_t stream) {
    const float* x   = (const float*)d_in[0];
    const int*  eidx = (const int*)d_in[1];
    const float* W1  = (const float*)d_in[2];
    const float* b1  = (const float*)d_in[3];
    const float* W2  = (const float*)d_in[4];
    const float* b2  = (const float*)d_in[5];

    const int IN = 96, HID = 96, OUT = 32;
    const int N = in_sizes[0] / IN;   // 50000 (<= 65536 for 16-bit packing)
    const int E = in_sizes[1] / 2;    // 800000
    const int* src = eidx;
    const int* dst = eidx + E;

    float* out  = (float*)d_out;
    float* x1   = out;                       // [N, 96] f32
    float* out2 = out + (size_t)N * HID;     // [N, 32] f32

    const int nbins = (N + 255) / 256;        // 196
    const int nblk = (E + CHUNK - 1) / CHUNK; // 391 (<= MAXBLK)

    auto align512 = [](size_t v) { return ((v + 511) / 512) * 512; };
    char* ws = (char*)d_ws;
    size_t off = 0;
    float* dinv     = (float*)(ws + off); off += align512((size_t)N * 4);
    int* row_ptr    = (int*)(ws + off);   off += align512((size_t)(N + 1) * 4);
    unsigned short* esrc = (unsigned short*)(ws + off); off += align512((size_t)E * 2);
    unsigned* slab  = (unsigned*)(ws + off); off += align512((size_t)E * 4);
    int* cntT       = (int*)(ws + off);   off += align512((size_t)NBINS_CAP * MAXBLK * 4);
    int* segT       = (int*)(ws + off);   off += align512((size_t)NBINS_CAP * MAXBLK * 4);
    int* btotal     = (int*)(ws + off);   off += align512(NBINS_CAP * 4);
    unsigned short* wtg  = (unsigned short*)(ws + off); off += align512(96 * WT_LD * 2);
    unsigned short* wtg2 = (unsigned short*)(ws + off); off += align512(32 * WT_LD * 2);
    unsigned short* hb   = (unsigned short*)(ws + off); off += align512((size_t)N * 96 * 2);

    // ---- CSR build (atomic-free) + fused W transposes ----
    binA_kernel<256><<<nblk, 256, 0, stream>>>(src, dst, slab, cntT, segT, nbins, E);
    binsum_kernel<<<nbins, 256, 0, stream>>>(cntT, btotal, W1, W2, wtg, wtg2, nbins, nblk);
    binB_kernel<<<nbins, 512, 0, stream>>>(slab, cntT, segT, btotal,
                                           dinv, row_ptr, esrc, N, nbins, nblk, E);

    // ---- Layer 1 (MFMA) ----
    gemm1_mfma<<<(N + 63) / 64, 256, 0, stream>>>(x, wtg, dinv, hb, N);
    agg_kernel<12, 16, true, 192><<<(N + 15) / 16, 192, 0, stream>>>(
        (const uint4*)hb, row_ptr, esrc, dinv, b1, x1, N);

    // ---- Layer 2 (MFMA) ----
    gemm2_mfma<<<(N + 63) / 64, 256, 0, stream>>>(x1, wtg2, dinv, hb, N);
    agg_kernel<4, 64, false, 256><<<(N + 63) / 64, 256, 0, stream>>>(
        (const uint4*)hb, row_ptr, esrc, dinv, b2, out2, N);
}